// Round 14
// baseline (54.263 us; speedup 1.0000x reference)
//
#include <hip/hip_runtime.h>

typedef float f32x4 __attribute__((ext_vector_type(4)));
typedef _Float16 f16x8 __attribute__((ext_vector_type(8)));
typedef __fp16 fp16x2 __attribute__((ext_vector_type(2)));

#define NEG_SLOPE 0.2f
#define MASK_EPS 1e-8f

// ---------------------------------------------------------------------------
// Kernel 1: pack (adj > eps) into transposed bitmask maskT[b][j][16 u32],
// float2-vectorized. Blocks with ic==0 also convert W -> wTf16 (f16 [n][k]).
// (R12-proven)
// ---------------------------------------------------------------------------
__global__ __launch_bounds__(256) void gat_mask_kernel(
    const float* __restrict__ adj, unsigned* __restrict__ maskT,
    const float* __restrict__ W, _Float16* __restrict__ wTf16) {
  const int b = blockIdx.x;            // 0..31
  const int ic = blockIdx.y;           // 0..15: 32-i word index
  const int tid = threadIdx.x;
  const int j = tid * 2;
  const float* ap = adj + (size_t)b * 262144 + (size_t)ic * 32 * 512 + j;
  unsigned w0 = 0, w1 = 0;
#pragma unroll
  for (int i = 0; i < 32; ++i) {
    float2 v = *(const float2*)(ap + (size_t)i * 512);
    w0 |= (v.x > MASK_EPS ? 1u : 0u) << i;
    w1 |= (v.y > MASK_EPS ? 1u : 0u) << i;
  }
  unsigned* mp = maskT + ((size_t)b * 512 + j) * 16 + ic;
  mp[0] = w0;
  mp[16] = w1;

  if (ic == 0) {                       // 32 blocks: W transpose+convert
    const int k = b * 4 + (tid >> 6);
    const int n = tid & 63;
    wTf16[(n) * 128 + k]      = (_Float16)W[k * 128 + n];
    wTf16[(n + 64) * 128 + k] = (_Float16)W[k * 128 + n + 64];
  }
}

// ---------------------------------------------------------------------------
// Kernel 2: Wh = h @ W via f16 MFMA. Zero LDS, zero barriers. (R7-proven)
// ---------------------------------------------------------------------------
__global__ __launch_bounds__(256, 4) void gat_wh_mfma(
    const float* __restrict__ h, const _Float16* __restrict__ wTf16,
    const float* __restrict__ a, _Float16* __restrict__ whT,
    float* __restrict__ sIT, float* __restrict__ sJT) {
  const int tid = threadIdx.x;
  const int bid = blockIdx.x;          // 0..1023, 16 rows each
  const int w = tid >> 6;              // wave = head
  const int lane = tid & 63;
  const int nl = lane & 15;
  const int ig = lane >> 4;
  const int row0 = bid * 16;
  const int bb = row0 >> 9;
  const int iloc = row0 & 511;

  const float* hP = h + (size_t)(row0 + nl) * 128 + ig * 8;
  const _Float16* wP0 = wTf16 + (size_t)(w * 32 + nl) * 128 + ig * 8;
  const _Float16* wP1 = wTf16 + (size_t)(w * 32 + 16 + nl) * 128 + ig * 8;

  f32x4 acc0 = {0.f, 0.f, 0.f, 0.f};
  f32x4 acc1 = {0.f, 0.f, 0.f, 0.f};

#pragma unroll
  for (int kt = 0; kt < 4; ++kt) {
    f32x4 ha = *(const f32x4*)(hP + kt * 32);
    f32x4 hb = *(const f32x4*)(hP + kt * 32 + 4);
    union { fp16x2 h2[4]; f16x8 v; } af;
    af.h2[0] = __builtin_amdgcn_cvt_pkrtz(ha.x, ha.y);
    af.h2[1] = __builtin_amdgcn_cvt_pkrtz(ha.z, ha.w);
    af.h2[2] = __builtin_amdgcn_cvt_pkrtz(hb.x, hb.y);
    af.h2[3] = __builtin_amdgcn_cvt_pkrtz(hb.z, hb.w);
    const f16x8 b0 = *(const f16x8*)(wP0 + kt * 32);
    const f16x8 b1 = *(const f16x8*)(wP1 + kt * 32);
    acc0 = __builtin_amdgcn_mfma_f32_16x16x32_f16(af.v, b0, acc0, 0, 0, 0);
    acc1 = __builtin_amdgcn_mfma_f32_16x16x32_f16(af.v, b1, acc1, 0, 0, 0);
  }

  const float avS0 = a[w * 64 + nl];
  const float avS1 = a[w * 64 + 16 + nl];
  const float avD0 = a[w * 64 + 32 + nl];
  const float avD1 = a[w * 64 + 48 + nl];

  float si[4], sj[4];
#pragma unroll
  for (int reg = 0; reg < 4; ++reg) {
    si[reg] = acc0[reg] * avS0 + acc1[reg] * avS1;
    sj[reg] = acc0[reg] * avD0 + acc1[reg] * avD1;
#pragma unroll
    for (int off = 1; off < 16; off <<= 1) {
      si[reg] += __shfl_xor(si[reg], off, 64);
      sj[reg] += __shfl_xor(sj[reg], off, 64);
    }
  }
  if (nl == 0) {
    const int base = bb * 2048 + w * 512 + iloc + ig * 4;
#pragma unroll
    for (int reg = 0; reg < 4; ++reg) {
      sIT[base + reg] = si[reg];
      sJT[base + reg] = sj[reg];
    }
  }

  union { fp16x2 h2[2]; float2 f2; } p0, p1;
  p0.h2[0] = __builtin_amdgcn_cvt_pkrtz(acc0[0], acc0[1]);
  p0.h2[1] = __builtin_amdgcn_cvt_pkrtz(acc0[2], acc0[3]);
  p1.h2[0] = __builtin_amdgcn_cvt_pkrtz(acc1[0], acc1[1]);
  p1.h2[1] = __builtin_amdgcn_cvt_pkrtz(acc1[2], acc1[3]);
  _Float16* wout = whT + (size_t)bb * 128 * 512 + iloc + ig * 4;
  *(float2*)(wout + (size_t)(w * 32 + nl) * 512)      = p0.f2;
  *(float2*)(wout + (size_t)(w * 32 + 16 + nl) * 512) = p1.f2;
}

// ---------------------------------------------------------------------------
// Kernel 3: attention+aggregate. Block = 1024 thr = 16 waves = 4 heads x 4
// i-quarters; j-tile 64 (each bf/si load feeds 8 MFMAs). launch_bounds
// (1024,1): VGPR cap >=128 so acc[4][2]+masks+prefetch live in registers
// (R13's (1024,4) capped at 64 -> 74 MB scratch spill). Explicit register
// double-buffer on per-t si/whT fragments (statically indexed, full unroll).
// i-quarters merged via 3-round LDS tree (additive: no max-subtraction).
// ---------------------------------------------------------------------------
__global__ __launch_bounds__(1024, 1) void gat_attn_kernel(
    const unsigned* __restrict__ maskT, const _Float16* __restrict__ whT,
    const float* __restrict__ sIT, const float* __restrict__ sJT,
    float* __restrict__ out) {
  __shared__ f32x4 ldsM[4][8][64];     // 32 KB: [hd][jg*2+dh][lane]
  __shared__ f32x4 ldsL[4][64];        // 4 KB:  [hd][lane] = l[0..3]

  const int tid = threadIdx.x;
  const int b = blockIdx.x;            // 0..31 (same-b -> same XCD)
  const int j0 = blockIdx.y * 64;      // 8 tiles
  const int w16 = tid >> 6;            // 0..15
  const int hd = w16 & 3;              // head
  const int ih = w16 >> 2;             // i-quarter (128 i each)
  const int lane = tid & 63;
  const int nl = lane & 15;
  const int ig = lane >> 4;

  float sj[4];
  unsigned mw[4][4];
#pragma unroll
  for (int jg = 0; jg < 4; ++jg) {
    sj[jg] = sJT[b * 2048 + hd * 512 + j0 + jg * 16 + nl];
    uint4 m = *(const uint4*)(maskT + ((size_t)b * 512 + j0 + jg * 16 + nl) * 16 + ih * 4);
    mw[jg][0] = m.x; mw[jg][1] = m.y; mw[jg][2] = m.z; mw[jg][3] = m.w;
  }

  const _Float16* whP = whT + (size_t)b * 65536 + (size_t)(hd * 32 + nl) * 512 + ih * 128 + ig * 8;
  const float* siP = sIT + b * 2048 + hd * 512 + ih * 128 + ig * 8;

  f32x4 acc[4][2];                     // [jg][d-half]
#pragma unroll
  for (int jg = 0; jg < 4; ++jg) {
    acc[jg][0] = (f32x4){0.f, 0.f, 0.f, 0.f};
    acc[jg][1] = (f32x4){0.f, 0.f, 0.f, 0.f};
  }
  float l[4] = {0.f, 0.f, 0.f, 0.f};

  // register double-buffer for per-t fragments
  f32x4 sA[2], sB[2];
  f16x8 bfa[2], bfb[2];
  sA[0] = *(const f32x4*)(siP);
  sB[0] = *(const f32x4*)(siP + 4);
  bfa[0] = *(const f16x8*)(whP);
  bfb[0] = *(const f16x8*)(whP + 16 * 512);

#pragma unroll
  for (int t = 0; t < 4; ++t) {        // 4 steps x 32 i = 128 i (quarter)
    const int cur = t & 1, nxt = cur ^ 1;
    if (t < 3) {                       // prefetch t+1 fragments
      const int idx = (t + 1) * 32;
      sA[nxt] = *(const f32x4*)(siP + idx);
      sB[nxt] = *(const f32x4*)(siP + idx + 4);
      bfa[nxt] = *(const f16x8*)(whP + idx);
      bfb[nxt] = *(const f16x8*)(whP + 16 * 512 + idx);
    }
    float si8[8] = {sA[cur].x, sA[cur].y, sA[cur].z, sA[cur].w,
                    sB[cur].x, sB[cur].y, sB[cur].z, sB[cur].w};
    const f16x8 bf0 = bfa[cur];
    const f16x8 bf1 = bfb[cur];

#pragma unroll
    for (int jg = 0; jg < 4; ++jg) {
      const unsigned bits = (mw[jg][t] >> (ig * 8)) & 0xffu;
      float p[8];
#pragma unroll
      for (int r = 0; r < 8; ++r) {
        float e = si8[r] + sj[jg];
        e = e >= 0.f ? e : NEG_SLOPE * e;
        p[r] = (bits & (1u << r)) ? __expf(e) : 0.f;
      }
      l[jg] += ((p[0] + p[1]) + (p[2] + p[3])) + ((p[4] + p[5]) + (p[6] + p[7]));

      union { fp16x2 h2[4]; f16x8 v; } af;
#pragma unroll
      for (int q = 0; q < 4; ++q)
        af.h2[q] = __builtin_amdgcn_cvt_pkrtz(p[2 * q], p[2 * q + 1]);

      acc[jg][0] = __builtin_amdgcn_mfma_f32_16x16x32_f16(af.v, bf0, acc[jg][0], 0, 0, 0);
      acc[jg][1] = __builtin_amdgcn_mfma_f32_16x16x32_f16(af.v, bf1, acc[jg][1], 0, 0, 0);
    }
  }

  // in-wave reduce l over the 4 ig-slices
#pragma unroll
  for (int jg = 0; jg < 4; ++jg) {
    l[jg] += __shfl_xor(l[jg], 16, 64);
    l[jg] += __shfl_xor(l[jg], 32, 64);
  }
  f32x4 lv = {l[0], l[1], l[2], l[3]};

  // ---- 3-round merge of the 4 i-quarters (single 36 KB buffer) ----
  if (ih == 1) {
#pragma unroll
    for (int jg = 0; jg < 4; ++jg) {
      ldsM[hd][jg * 2][lane] = acc[jg][0];
      ldsM[hd][jg * 2 + 1][lane] = acc[jg][1];
    }
    ldsL[hd][lane] = lv;
  }
  __syncthreads();
  if (ih == 0) {
#pragma unroll
    for (int jg = 0; jg < 4; ++jg) {
      acc[jg][0] += ldsM[hd][jg * 2][lane];
      acc[jg][1] += ldsM[hd][jg * 2 + 1][lane];
    }
    lv += ldsL[hd][lane];
  }
  __syncthreads();
  if (ih == 3) {
#pragma unroll
    for (int jg = 0; jg < 4; ++jg) {
      ldsM[hd][jg * 2][lane] = acc[jg][0];
      ldsM[hd][jg * 2 + 1][lane] = acc[jg][1];
    }
    ldsL[hd][lane] = lv;
  }
  __syncthreads();
  if (ih == 2) {
#pragma unroll
    for (int jg = 0; jg < 4; ++jg) {
      acc[jg][0] += ldsM[hd][jg * 2][lane];
      acc[jg][1] += ldsM[hd][jg * 2 + 1][lane];
    }
    lv += ldsL[hd][lane];
  }
  __syncthreads();
  if (ih == 2) {
#pragma unroll
    for (int jg = 0; jg < 4; ++jg) {
      ldsM[hd][jg * 2][lane] = acc[jg][0];
      ldsM[hd][jg * 2 + 1][lane] = acc[jg][1];
    }
    ldsL[hd][lane] = lv;
  }
  __syncthreads();
  if (ih == 0) {
#pragma unroll
    for (int jg = 0; jg < 4; ++jg) {
      acc[jg][0] += ldsM[hd][jg * 2][lane];
      acc[jg][1] += ldsM[hd][jg * 2 + 1][lane];
    }
    lv += ldsL[hd][lane];

    // ---- normalize + store (D layout: row = 4*ig + reg, col = nl) ----
    float* outB = out + ((size_t)b * 512 + j0) * 128 + hd * 32;
#pragma unroll
    for (int jg = 0; jg < 4; ++jg) {
#pragma unroll
      for (int reg = 0; reg < 4; ++reg) {
        const int jr = 4 * ig + reg;
        const float rl = 1.0f / __shfl(lv[jg], jr, 64);
        outB[(size_t)(jg * 16 + jr) * 128 + nl]      = acc[jg][0][reg] * rl;
        outB[(size_t)(jg * 16 + jr) * 128 + 16 + nl] = acc[jg][1][reg] * rl;
      }
    }
  }
}

extern "C" void kernel_launch(void* const* d_in, const int* in_sizes, int n_in,
                              void* d_out, int out_size, void* d_ws, size_t ws_size,
                              hipStream_t stream) {
  const float* h = (const float*)d_in[0];     // (32, 512, 128)
  const float* adj = (const float*)d_in[1];   // (32, 512, 512)
  const float* W = (const float*)d_in[2];     // (128, 128)
  const float* a = (const float*)d_in[3];     // (4, 64)
  float* out = (float*)d_out;                 // (32, 512, 128)

  _Float16* whT = (_Float16*)d_ws;                      // 4 MB
  float* sIT = (float*)(whT + (size_t)32 * 128 * 512);  // 256 KB
  float* sJT = sIT + (size_t)32 * 4 * 512;              // 256 KB
  unsigned* maskT = (unsigned*)(sJT + (size_t)32 * 4 * 512);      // 1 MB
  _Float16* wTf16 = (_Float16*)(maskT + (size_t)32 * 512 * 16);   // 32 KB

  gat_mask_kernel<<<dim3(32, 16), dim3(256), 0, stream>>>(adj, maskT, W, wTf16);
  gat_wh_mfma<<<dim3(1024), dim3(256), 0, stream>>>(h, wTf16, a, whT, sIT, sJT);
  gat_attn_kernel<<<dim3(32, 8), dim3(1024), 0, stream>>>(maskT, whT, sIT, sJT, out);
}

// Round 15
// 44.843 us; speedup vs baseline: 1.2101x; 1.2101x over previous
//
#include <hip/hip_runtime.h>

typedef float f32x4 __attribute__((ext_vector_type(4)));
typedef _Float16 f16x8 __attribute__((ext_vector_type(8)));
typedef __fp16 fp16x2 __attribute__((ext_vector_type(2)));

#define NEG_SLOPE 0.2f
#define MASK_EPS 1e-8f

// ---------------------------------------------------------------------------
// Kernel 1: pack (adj > eps) into transposed bitmask maskT[b][j][16 u32],
// float2-vectorized. Blocks with ic==0 also convert W -> wTf16 (f16 [n][k]).
// (R12-proven)
// ---------------------------------------------------------------------------
__global__ __launch_bounds__(256) void gat_mask_kernel(
    const float* __restrict__ adj, unsigned* __restrict__ maskT,
    const float* __restrict__ W, _Float16* __restrict__ wTf16) {
  const int b = blockIdx.x;            // 0..31
  const int ic = blockIdx.y;           // 0..15: 32-i word index
  const int tid = threadIdx.x;
  const int j = tid * 2;
  const float* ap = adj + (size_t)b * 262144 + (size_t)ic * 32 * 512 + j;
  unsigned w0 = 0, w1 = 0;
#pragma unroll
  for (int i = 0; i < 32; ++i) {
    float2 v = *(const float2*)(ap + (size_t)i * 512);
    w0 |= (v.x > MASK_EPS ? 1u : 0u) << i;
    w1 |= (v.y > MASK_EPS ? 1u : 0u) << i;
  }
  unsigned* mp = maskT + ((size_t)b * 512 + j) * 16 + ic;
  mp[0] = w0;
  mp[16] = w1;

  if (ic == 0) {                       // 32 blocks: W transpose+convert
    const int k = b * 4 + (tid >> 6);
    const int n = tid & 63;
    wTf16[(n) * 128 + k]      = (_Float16)W[k * 128 + n];
    wTf16[(n + 64) * 128 + k] = (_Float16)W[k * 128 + n + 64];
  }
}

// ---------------------------------------------------------------------------
// Kernel 2: Wh = h @ W via f16 MFMA. Zero LDS, zero barriers. (R7-proven)
// Epilogue now writes whT in BLOCKED layout [b][h][it=16][d=32][i32=32]
// (2KB contiguous 32x32 f16 tiles) so attn B-frag loads are coalesced.
// ---------------------------------------------------------------------------
__global__ __launch_bounds__(256, 4) void gat_wh_mfma(
    const float* __restrict__ h, const _Float16* __restrict__ wTf16,
    const float* __restrict__ a, _Float16* __restrict__ whT,
    float* __restrict__ sIT, float* __restrict__ sJT) {
  const int tid = threadIdx.x;
  const int bid = blockIdx.x;          // 0..1023, 16 rows each
  const int w = tid >> 6;              // wave = head
  const int lane = tid & 63;
  const int nl = lane & 15;
  const int ig = lane >> 4;
  const int row0 = bid * 16;
  const int bb = row0 >> 9;
  const int iloc = row0 & 511;

  const float* hP = h + (size_t)(row0 + nl) * 128 + ig * 8;
  const _Float16* wP0 = wTf16 + (size_t)(w * 32 + nl) * 128 + ig * 8;
  const _Float16* wP1 = wTf16 + (size_t)(w * 32 + 16 + nl) * 128 + ig * 8;

  f32x4 acc0 = {0.f, 0.f, 0.f, 0.f};
  f32x4 acc1 = {0.f, 0.f, 0.f, 0.f};

#pragma unroll
  for (int kt = 0; kt < 4; ++kt) {
    f32x4 ha = *(const f32x4*)(hP + kt * 32);
    f32x4 hb = *(const f32x4*)(hP + kt * 32 + 4);
    union { fp16x2 h2[4]; f16x8 v; } af;
    af.h2[0] = __builtin_amdgcn_cvt_pkrtz(ha.x, ha.y);
    af.h2[1] = __builtin_amdgcn_cvt_pkrtz(ha.z, ha.w);
    af.h2[2] = __builtin_amdgcn_cvt_pkrtz(hb.x, hb.y);
    af.h2[3] = __builtin_amdgcn_cvt_pkrtz(hb.z, hb.w);
    const f16x8 b0 = *(const f16x8*)(wP0 + kt * 32);
    const f16x8 b1 = *(const f16x8*)(wP1 + kt * 32);
    acc0 = __builtin_amdgcn_mfma_f32_16x16x32_f16(af.v, b0, acc0, 0, 0, 0);
    acc1 = __builtin_amdgcn_mfma_f32_16x16x32_f16(af.v, b1, acc1, 0, 0, 0);
  }

  const float avS0 = a[w * 64 + nl];
  const float avS1 = a[w * 64 + 16 + nl];
  const float avD0 = a[w * 64 + 32 + nl];
  const float avD1 = a[w * 64 + 48 + nl];

  float si[4], sj[4];
#pragma unroll
  for (int reg = 0; reg < 4; ++reg) {
    si[reg] = acc0[reg] * avS0 + acc1[reg] * avS1;
    sj[reg] = acc0[reg] * avD0 + acc1[reg] * avD1;
#pragma unroll
    for (int off = 1; off < 16; off <<= 1) {
      si[reg] += __shfl_xor(si[reg], off, 64);
      sj[reg] += __shfl_xor(sj[reg], off, 64);
    }
  }
  if (nl == 0) {
    const int base = bb * 2048 + w * 512 + iloc + ig * 4;
#pragma unroll
    for (int reg = 0; reg < 4; ++reg) {
      sIT[base + reg] = si[reg];
      sJT[base + reg] = sj[reg];
    }
  }

  // blocked whT write: i_base = iloc + ig*4 (4 consecutive i in one tile)
  union { fp16x2 h2[2]; float2 f2; } p0, p1;
  p0.h2[0] = __builtin_amdgcn_cvt_pkrtz(acc0[0], acc0[1]);
  p0.h2[1] = __builtin_amdgcn_cvt_pkrtz(acc0[2], acc0[3]);
  p1.h2[0] = __builtin_amdgcn_cvt_pkrtz(acc1[0], acc1[1]);
  p1.h2[1] = __builtin_amdgcn_cvt_pkrtz(acc1[2], acc1[3]);
  const int i_base = iloc + ig * 4;
  const int it = i_base >> 5, i32 = i_base & 31;
  _Float16* wout = whT + (size_t)bb * 65536 + (size_t)w * 16384 + it * 1024 + i32;
  *(float2*)(wout + nl * 32)        = p0.f2;   // dd = nl
  *(float2*)(wout + (16 + nl) * 32) = p1.f2;   // dd = 16+nl
}

// ---------------------------------------------------------------------------
// Kernel 3: attention+aggregate (R12 structure, blocked-whT loads).
// Block = 512 thr = 8 waves = 4 heads x 2 i-halves; j-tile 32. B-frag loads
// now 1KB contiguous per wave (lane offset nl*32+ig*8 covers [0,512) halfs).
// Mask bits in regs; i-halves merged via one LDS exchange + barrier.
// ---------------------------------------------------------------------------
__global__ __launch_bounds__(512, 4) void gat_attn_kernel(
    const unsigned* __restrict__ maskT, const _Float16* __restrict__ whT,
    const float* __restrict__ sIT, const float* __restrict__ sJT,
    float* __restrict__ out) {
  __shared__ float ldsA[4][64][17];    // [head][lane][16 acc + pad]
  __shared__ float ldsL[4][2][64];

  const int tid = threadIdx.x;
  const int b = blockIdx.x;            // 0..31 (same-b blocks -> same XCD)
  const int j0 = blockIdx.y * 32;      // 16 tiles
  const int w8 = tid >> 6;             // 0..7
  const int hd = w8 & 3;               // head
  const int ih = w8 >> 2;              // i-half
  const int lane = tid & 63;
  const int nl = lane & 15;
  const int ig = lane >> 4;

  const float sj0 = sJT[b * 2048 + hd * 512 + j0 + nl];
  const float sj1 = sJT[b * 2048 + hd * 512 + j0 + 16 + nl];

  const unsigned* mP0 = maskT + ((size_t)b * 512 + j0 + nl) * 16 + ih * 8;
  const unsigned* mP1 = maskT + ((size_t)b * 512 + j0 + 16 + nl) * 16 + ih * 8;
  uint4 mA = *(const uint4*)(mP0);
  uint4 mB = *(const uint4*)(mP0 + 4);
  uint4 mC = *(const uint4*)(mP1);
  uint4 mD = *(const uint4*)(mP1 + 4);
  const unsigned mw0[8] = {mA.x, mA.y, mA.z, mA.w, mB.x, mB.y, mB.z, mB.w};
  const unsigned mw1[8] = {mC.x, mC.y, mC.z, mC.w, mD.x, mD.y, mD.z, mD.w};

  // blocked whT: [b][hd][it=16][dd=32][i32=32]; this wave covers it = ih*8 .. ih*8+7
  const _Float16* whP = whT + (size_t)b * 65536 + (size_t)hd * 16384
                        + (size_t)(ih * 8) * 1024 + nl * 32 + ig * 8;
  const float* siP = sIT + b * 2048 + hd * 512 + ih * 256 + ig * 8;

  f32x4 acc00 = {0.f, 0.f, 0.f, 0.f}, acc01 = {0.f, 0.f, 0.f, 0.f};
  f32x4 acc10 = {0.f, 0.f, 0.f, 0.f}, acc11 = {0.f, 0.f, 0.f, 0.f};
  float l0 = 0.f, l1 = 0.f;

#pragma unroll
  for (int t = 0; t < 4; ++t) {
#pragma unroll
    for (int ks = 0; ks < 2; ++ks) {
      const int st = t * 2 + ks;       // 32-i step 0..7
      f32x4 sA = *(const f32x4*)(siP + st * 32);
      f32x4 sB = *(const f32x4*)(siP + st * 32 + 4);
      const f16x8 bf0 = *(const f16x8*)(whP + st * 1024);        // dd = nl
      const f16x8 bf1 = *(const f16x8*)(whP + st * 1024 + 512);  // dd = 16+nl
      const unsigned bits0 = (mw0[st] >> (ig * 8)) & 0xffu;
      const unsigned bits1 = (mw1[st] >> (ig * 8)) & 0xffu;

      float si[8] = {sA.x, sA.y, sA.z, sA.w, sB.x, sB.y, sB.z, sB.w};
      float p0[8], p1[8];
#pragma unroll
      for (int r = 0; r < 8; ++r) {
        float e0 = si[r] + sj0;
        e0 = e0 >= 0.f ? e0 : NEG_SLOPE * e0;
        p0[r] = (bits0 & (1u << r)) ? __expf(e0) : 0.f;
        float e1 = si[r] + sj1;
        e1 = e1 >= 0.f ? e1 : NEG_SLOPE * e1;
        p1[r] = (bits1 & (1u << r)) ? __expf(e1) : 0.f;
      }
      l0 += ((p0[0] + p0[1]) + (p0[2] + p0[3])) + ((p0[4] + p0[5]) + (p0[6] + p0[7]));
      l1 += ((p1[0] + p1[1]) + (p1[2] + p1[3])) + ((p1[4] + p1[5]) + (p1[6] + p1[7]));

      union { fp16x2 h2[4]; f16x8 v; } af0, af1;
#pragma unroll
      for (int q = 0; q < 4; ++q) {
        af0.h2[q] = __builtin_amdgcn_cvt_pkrtz(p0[2 * q], p0[2 * q + 1]);
        af1.h2[q] = __builtin_amdgcn_cvt_pkrtz(p1[2 * q], p1[2 * q + 1]);
      }

      acc00 = __builtin_amdgcn_mfma_f32_16x16x32_f16(af0.v, bf0, acc00, 0, 0, 0);
      acc01 = __builtin_amdgcn_mfma_f32_16x16x32_f16(af0.v, bf1, acc01, 0, 0, 0);
      acc10 = __builtin_amdgcn_mfma_f32_16x16x32_f16(af1.v, bf0, acc10, 0, 0, 0);
      acc11 = __builtin_amdgcn_mfma_f32_16x16x32_f16(af1.v, bf1, acc11, 0, 0, 0);
    }
  }

  // reduce l over the 4 ig-slices (within wave)
  l0 += __shfl_xor(l0, 16, 64); l0 += __shfl_xor(l0, 32, 64);
  l1 += __shfl_xor(l1, 16, 64); l1 += __shfl_xor(l1, 32, 64);

  // ---- merge i-halves via LDS (waves 4..7 publish, 0..3 absorb) ----
  if (ih == 1) {
    float* dst = &ldsA[hd][lane][0];
#pragma unroll
    for (int q = 0; q < 4; ++q) {
      dst[q] = acc00[q]; dst[4 + q] = acc01[q];
      dst[8 + q] = acc10[q]; dst[12 + q] = acc11[q];
    }
    ldsL[hd][0][lane] = l0;
    ldsL[hd][1][lane] = l1;
  }
  __syncthreads();
  if (ih == 0) {
    const float* src = &ldsA[hd][lane][0];
#pragma unroll
    for (int q = 0; q < 4; ++q) {
      acc00[q] += src[q]; acc01[q] += src[4 + q];
      acc10[q] += src[8 + q]; acc11[q] += src[12 + q];
    }
    const float lt0 = l0 + ldsL[hd][0][lane];
    const float lt1 = l1 + ldsL[hd][1][lane];

    float* outB = out + ((size_t)b * 512 + j0) * 128 + hd * 32;
#pragma unroll
    for (int reg = 0; reg < 4; ++reg) {
      const int jr = 4 * ig + reg;
      const float rl0 = 1.0f / __shfl(lt0, jr, 64);
      const float rl1 = 1.0f / __shfl(lt1, jr, 64);
      outB[(size_t)jr * 128 + nl]             = acc00[reg] * rl0;
      outB[(size_t)jr * 128 + 16 + nl]        = acc01[reg] * rl0;
      outB[(size_t)(16 + jr) * 128 + nl]      = acc10[reg] * rl1;
      outB[(size_t)(16 + jr) * 128 + 16 + nl] = acc11[reg] * rl1;
    }
  }
}

extern "C" void kernel_launch(void* const* d_in, const int* in_sizes, int n_in,
                              void* d_out, int out_size, void* d_ws, size_t ws_size,
                              hipStream_t stream) {
  const float* h = (const float*)d_in[0];     // (32, 512, 128)
  const float* adj = (const float*)d_in[1];   // (32, 512, 512)
  const float* W = (const float*)d_in[2];     // (128, 128)
  const float* a = (const float*)d_in[3];     // (4, 64)
  float* out = (float*)d_out;                 // (32, 512, 128)

  _Float16* whT = (_Float16*)d_ws;                      // 4 MB (blocked layout)
  float* sIT = (float*)(whT + (size_t)32 * 128 * 512);  // 256 KB
  float* sJT = sIT + (size_t)32 * 4 * 512;              // 256 KB
  unsigned* maskT = (unsigned*)(sJT + (size_t)32 * 4 * 512);      // 1 MB
  _Float16* wTf16 = (_Float16*)(maskT + (size_t)32 * 512 * 16);   // 32 KB

  gat_mask_kernel<<<dim3(32, 16), dim3(256), 0, stream>>>(adj, maskT, W, wTf16);
  gat_wh_mfma<<<dim3(1024), dim3(256), 0, stream>>>(h, wTf16, a, whT, sIT, sJT);
  gat_attn_kernel<<<dim3(32, 16), dim3(512), 0, stream>>>(maskT, whT, sIT, sJT, out);
}